// Round 3
// baseline (809.250 us; speedup 1.0000x reference)
//
#include <hip/hip_runtime.h>
#include <hip/hip_cooperative_groups.h>

namespace cg = cooperative_groups;

#define NB2   2048      // histogram buckets over [0,1)
#define CAP2  2048      // per-batch collect capacity (expected ~128 in threshold bucket)
#define BATCH 32
#define NTOK  262144    // 512*512
#define GRID  1024      // blocks (cooperative) -> 32 blocks per batch
#define BLOCK 256
#define BPB   32        // blocks per batch
#define SLICE 8192      // floats of smap per block (NTOK / BPB)

__device__ __forceinline__ int bucket2(float v) {
    int b = (int)(v * (float)NB2);
    return b > NB2 - 1 ? NB2 - 1 : b;
}

__device__ __forceinline__ float token_loss(float d0, float d1, float u0, float u1,
                                            bool sel) {
    float g0 = -__logf(-__logf(u0));
    float g1 = -__logf(-__logf(u1));
    float dd = (d0 + g0) - (d1 + g1);
    float l  = __logf(1.f + __expf(-fabsf(dd)));
    float lp0 = (dd >= 0.f) ? -l      : dd - l;
    float lp1 = (dd >= 0.f) ? -l - dd : -l;
    lp0 = fmaxf(lp0, -100.f); lp1 = fmaxf(lp1, -100.f);
    return sel ? -lp0 : -lp1;
}

// One cooperative kernel: hist -> select -> collect -> refine -> loss -> reduce.
// LDS: smem[4096] ints (16 KB, overlaid per phase) + red[4].
__global__ __launch_bounds__(BLOCK, 8) void mega_kernel(
        const float* __restrict__ ds, const float* __restrict__ smap,
        const float* __restrict__ u, const int* __restrict__ kptr,
        int* __restrict__ hist,      // BATCH*NB2, then cnt[BATCH] contiguous
        int* __restrict__ tbR,       // 2*BATCH
        float* __restrict__ T, int* __restrict__ ncut,
        float* __restrict__ cval, int* __restrict__ cidx,   // BATCH*CAP2 each
        float* __restrict__ partials,                        // GRID
        float* __restrict__ out) {
    cg::grid_group grid = cg::this_grid();
    __shared__ int smem[4096];
    __shared__ float red[4];
    const int tid = threadIdx.x;
    const int blk = blockIdx.x;
    const int b   = blk >> 5;    // batch
    const int cb  = blk & 31;    // slice within batch
    int* cnt = hist + BATCH * NB2;

    // ---- phase 0a: zero global hist+cnt (contiguous: BATCH*NB2 + BATCH ints) ----
    {
        const int total = BATCH * NB2 + BATCH;
        for (int i = blk * BLOCK + tid; i < total; i += GRID * BLOCK) hist[i] = 0;
    }
    // ---- phase 0b: LDS histogram of this block's smap slice ----
    int* lh = smem;
    for (int i = tid; i < NB2; i += BLOCK) lh[i] = 0;
    __syncthreads();
    const float4* src = (const float4*)(smap + (size_t)b * NTOK + (size_t)cb * SLICE);
    for (int i = tid; i < SLICE / 4; i += BLOCK) {
        float4 v = src[i];
        atomicAdd(&lh[bucket2(v.x)], 1);
        atomicAdd(&lh[bucket2(v.y)], 1);
        atomicAdd(&lh[bucket2(v.z)], 1);
        atomicAdd(&lh[bucket2(v.w)], 1);
    }
    __syncthreads();
    grid.sync();   // global hist zeroing complete everywhere

    // ---- phase 1: flush LDS hist to global ----
    {
        int* gh = hist + b * NB2;
        for (int i = tid; i < NB2; i += BLOCK) {
            int c = lh[i];
            if (c) atomicAdd(&gh[i], c);
        }
    }
    grid.sync();

    // ---- phase 2: select threshold bucket tb + residual rank R (blocks cb==0) ----
    if (cb == 0) {
        int* h     = smem;          // NB2
        int* csum  = smem + NB2;    // 256
        int* above = smem + NB2 + 256;
        const int C = NB2 / BLOCK;  // 8 buckets/thread
        const int* gh = hist + b * NB2;
        int base = tid * C;
        int s = 0;
        for (int i = 0; i < C; i++) { int v = gh[base + i]; h[base + i] = v; s += v; }
        csum[tid] = s;
        __syncthreads();
        if (tid == 0) {
            int acc = 0;
            for (int c = BLOCK - 1; c >= 0; c--) { above[c] = acc; acc += csum[c]; }
        }
        __syncthreads();
        int K = *kptr;
        int cum = above[tid];
        for (int i = C - 1; i >= 0; i--) {
            int hb = h[base + i];
            if (cum < K && cum + hb >= K) {
                tbR[2 * b]     = base + i;
                tbR[2 * b + 1] = K - cum;
            }
            cum += hb;
        }
    }
    grid.sync();

    // ---- phase 3: collect (value,index) of elements in threshold bucket ----
    {
        int tb = tbR[2 * b];
        int base_n = cb * SLICE;
        for (int i = tid; i < SLICE / 4; i += BLOCK) {
            float4 v = src[i];
            float vals[4] = {v.x, v.y, v.z, v.w};
#pragma unroll
            for (int s = 0; s < 4; s++) {
                if (bucket2(vals[s]) == tb) {
                    int p = atomicAdd(&cnt[b], 1);
                    if (p < CAP2) {
                        cval[b * CAP2 + p] = vals[s];
                        cidx[b * CAP2 + p] = base_n + 4 * i + s;
                    }
                }
            }
        }
    }
    grid.sync();

    // ---- phase 4: exact rank-(R-1) under (value desc, index asc) (blocks cb==0) ----
    if (cb == 0) {
        int R = tbR[2 * b + 1];
        int M = cnt[b];
        bool ovf = (M > CAP2);
        if (M > CAP2) M = CAP2;
        float* sv = (float*)smem;       // CAP2
        int*   si = smem + CAP2;        // CAP2
        for (int i = tid; i < M; i += BLOCK) {
            sv[i] = cval[b * CAP2 + i];
            si[i] = cidx[b * CAP2 + i];
        }
        __syncthreads();
        if (ovf || R > M || R < 1) {
            if (tid == 0) { T[b] = (float)tbR[2 * b] / (float)NB2; ncut[b] = 0x7fffffff; }
        } else {
            for (int i = tid; i < M; i += BLOCK) {
                float vi = sv[i]; int ii = si[i];
                int r = 0;
                for (int j = 0; j < M; j++) {
                    float vj = sv[j];
                    r += (vj > vi) || (vj == vi && si[j] < ii);
                }
                if (r == R - 1) { T[b] = vi; ncut[b] = ii; }  // unique rank
            }
        }
    }
    grid.sync();

    // ---- phase 5: fused loss over this block's 8192 tokens (32/thread) ----
    {
        float Tb = T[b];
        int   nc = ncut[b];
        const float4* ds4 = (const float4*)(ds + (size_t)b * NTOK * 2);
        const float4* u4  = (const float4*)(u  + (size_t)b * NTOK * 2);
        const float4* s4  = (const float4*)(smap + (size_t)b * NTOK);
        float acc = 0.f;
        for (int it = 0; it < 8; it++) {
            int p = cb * (SLICE / 4) + it * BLOCK + tid;  // float4-group of smap
            float4 dA = ds4[2 * p];
            float4 dB = ds4[2 * p + 1];
            float4 uA = u4[2 * p];
            float4 uB = u4[2 * p + 1];
            float4 sv4 = s4[p];
            int n0 = p << 2;
            bool s0 = (sv4.x > Tb) || (sv4.x == Tb && (n0 + 0) <= nc);
            bool s1 = (sv4.y > Tb) || (sv4.y == Tb && (n0 + 1) <= nc);
            bool s2 = (sv4.z > Tb) || (sv4.z == Tb && (n0 + 2) <= nc);
            bool s3 = (sv4.w > Tb) || (sv4.w == Tb && (n0 + 3) <= nc);
            acc += token_loss(dA.x, dA.y, uA.x, uA.y, s0)
                 + token_loss(dA.z, dA.w, uA.z, uA.w, s1)
                 + token_loss(dB.x, dB.y, uB.x, uB.y, s2)
                 + token_loss(dB.z, dB.w, uB.z, uB.w, s3);
        }
        for (int off = 32; off > 0; off >>= 1) acc += __shfl_down(acc, off, 64);
        int lane = tid & 63, wv = tid >> 6;
        if (lane == 0) red[wv] = acc;
        __syncthreads();
        if (tid == 0) partials[blk] = red[0] + red[1] + red[2] + red[3];
    }
    grid.sync();

    // ---- phase 6: block 0 reduces GRID partials -> out[0] ----
    if (blk == 0) {
        float acc = 0.f;
        for (int i = tid; i < GRID; i += BLOCK) acc += partials[i];
        for (int off = 32; off > 0; off >>= 1) acc += __shfl_down(acc, off, 64);
        int lane = tid & 63, wv = tid >> 6;
        if (lane == 0) red[wv] = acc;
        __syncthreads();
        if (tid == 0) out[0] = red[0] + red[1] + red[2] + red[3];
    }
}

extern "C" void kernel_launch(void* const* d_in, const int* in_sizes, int n_in,
                              void* d_out, int out_size, void* d_ws, size_t ws_size,
                              hipStream_t stream) {
    const float* ds   = (const float*)d_in[0];   // [B, N, 2]
    const float* smap = (const float*)d_in[1];   // [B, 1, H, W] == [B, N]
    const float* u    = (const float*)d_in[2];   // [B, N, 2]
    const int*   kptr = (const int*)d_in[3];     // scalar K

    // workspace layout (hist and cnt contiguous for one zeroing loop)
    int*   hist = (int*)d_ws;                    // BATCH*NB2 + BATCH (cnt)
    int*   tbR  = hist + BATCH * NB2 + BATCH;    // 2*BATCH
    float* T    = (float*)(tbR + 2 * BATCH);     // BATCH
    int*   ncut = (int*)(T + BATCH);             // BATCH
    float* cval = (float*)(ncut + BATCH);        // BATCH*CAP2
    int*   cidx = (int*)(cval + BATCH * CAP2);   // BATCH*CAP2
    float* partials = (float*)(cidx + BATCH * CAP2);  // GRID
    float* out = (float*)d_out;

    void* args[] = {(void*)&ds, (void*)&smap, (void*)&u, (void*)&kptr,
                    (void*)&hist, (void*)&tbR, (void*)&T, (void*)&ncut,
                    (void*)&cval, (void*)&cidx, (void*)&partials, (void*)&out};
    hipLaunchCooperativeKernel((void*)mega_kernel, dim3(GRID), dim3(BLOCK),
                               args, 0, stream);
}

// Round 4
// 233.878 us; speedup vs baseline: 3.4601x; 3.4601x over previous
//
#include <hip/hip_runtime.h>

#define NB    4096      // histogram buckets over [0,1)
#define CAP   1024      // per-batch collect capacity (expected ~64 in threshold bucket)
#define BATCH 32
#define NTOK  262144    // 512*512
#define PT    1024      // prep threads per block
#define LOSS_BLOCKS 4096   // B*NTOK / 8 tokens-per-thread / 256 threads

__device__ __forceinline__ int bucket_of(float v) {
    int b = (int)(v * (float)NB);
    return b > NB - 1 ? NB - 1 : b;
}

// --- Pass 1: per-batch FUSED selection: hist -> select -> collect -> refine ---
// One block per batch (32 blocks x 1024 threads). Everything in LDS; no global
// histogram, no memset, no cross-block deps. Outputs T[b], ncut[b].
__global__ __launch_bounds__(PT) void prep_kernel(const float* __restrict__ smap,
                                                  const int* __restrict__ kptr,
                                                  float* __restrict__ T,
                                                  int* __restrict__ ncut) {
    __shared__ int   hist[NB];       // 16 KB
    __shared__ int   sA[PT];         // suffix-scan ping
    __shared__ int   sB[PT];         // suffix-scan pong
    __shared__ float sv[CAP];
    __shared__ int   si[CAP];
    __shared__ int   cnt_s, tb_s, R_s;

    const int tid = threadIdx.x;
    const int b   = blockIdx.x;

    for (int i = tid; i < NB; i += PT) hist[i] = 0;
    if (tid == 0) cnt_s = 0;
    __syncthreads();

    // histogram of this batch's 262144 values (64 float4 iters/thread)
    const float4* src = (const float4*)(smap + (size_t)b * NTOK);
    const int NF4 = NTOK / 4;   // 65536
    for (int i = tid; i < NF4; i += PT) {
        float4 v = src[i];
        atomicAdd(&hist[bucket_of(v.x)], 1);
        atomicAdd(&hist[bucket_of(v.y)], 1);
        atomicAdd(&hist[bucket_of(v.z)], 1);
        atomicAdd(&hist[bucket_of(v.w)], 1);
    }
    __syncthreads();

    // chunk sums: thread t owns buckets [4t, 4t+4)
    const int C = NB / PT;  // 4
    int base = tid * C;
    int csum = hist[base] + hist[base + 1] + hist[base + 2] + hist[base + 3];
    sA[tid] = csum;
    __syncthreads();

    // Hillis-Steele inclusive SUFFIX scan over 1024 chunk sums (10 steps)
    int* pin = sA; int* pout = sB;
    for (int st = 1; st < PT; st <<= 1) {
        int v = pin[tid] + ((tid + st < PT) ? pin[tid + st] : 0);
        pout[tid] = v;
        __syncthreads();
        int* t_ = pin; pin = pout; pout = t_;
    }
    // pin[t] = sum of csum[t..1023]; count strictly above chunk t:
    int above = (tid < PT - 1) ? pin[tid + 1] : 0;

    const int K = *kptr;
    int cum = above;
    for (int i = C - 1; i >= 0; i--) {
        int hb = hist[base + i];
        if (cum < K && cum + hb >= K) { tb_s = base + i; R_s = K - cum; }
        cum += hb;
    }
    __syncthreads();
    const int tb = tb_s, R = R_s;

    // collect all (value, index) in bucket tb (re-read is L1/L2-hot)
    for (int i = tid; i < NF4; i += PT) {
        float4 v = src[i];
        float vals[4] = {v.x, v.y, v.z, v.w};
#pragma unroll
        for (int c = 0; c < 4; c++) {
            if (bucket_of(vals[c]) == tb) {
                int p = atomicAdd(&cnt_s, 1);
                if (p < CAP) { sv[p] = vals[c]; si[p] = 4 * i + c; }
            }
        }
    }
    __syncthreads();

    int M = cnt_s;
    if (M > CAP || R > M || R < 1) {   // statistically unreachable fallback
        if (tid == 0) { T[b] = (float)tb / (float)NB; ncut[b] = 0x7fffffff; }
        return;
    }
    // exact rank-(R-1) under (value desc, index asc); unique rank -> one writer
    for (int i = tid; i < M; i += PT) {
        float vi = sv[i]; int ii = si[i];
        int r = 0;
        for (int j = 0; j < M; j++) {
            float vj = sv[j];
            r += (vj > vi) || (vj == vi && si[j] < ii);
        }
        if (r == R - 1) { T[b] = vi; ncut[b] = ii; }
    }
}

__device__ __forceinline__ float token_loss(float d0, float d1, float u0, float u1,
                                            bool sel) {
    float g0 = -__logf(-__logf(u0));
    float g1 = -__logf(-__logf(u1));
    float dd = (d0 + g0) - (d1 + g1);
    float l  = __logf(1.f + __expf(-fabsf(dd)));
    float lp0 = (dd >= 0.f) ? -l      : dd - l;
    float lp1 = (dd >= 0.f) ? -l - dd : -l;
    lp0 = fmaxf(lp0, -100.f); lp1 = fmaxf(lp1, -100.f);
    return sel ? -lp0 : -lp1;
}

// --- Pass 2: fused gumbel-softmax BCE loss, 8 tokens/thread, per-block partials ---
__global__ void loss_kernel(const float* __restrict__ ds, const float* __restrict__ u,
                            const float* __restrict__ smap, const float* __restrict__ T,
                            const int* __restrict__ ncut, float* __restrict__ partials) {
    int tid = blockIdx.x * blockDim.x + threadIdx.x;  // one thread = 8 tokens
    int b  = tid >> 15;              // NTOK/8 = 32768 = 2^15 threads per batch
    int p8 = tid & 32767;            // 8-token group within batch
    const float4* ds4 = (const float4*)(ds + (size_t)b * NTOK * 2);
    const float4* u4  = (const float4*)(u  + (size_t)b * NTOK * 2);
    const float4* s4  = (const float4*)(smap + (size_t)b * NTOK);

    float4 d0 = ds4[4 * p8 + 0];
    float4 d1 = ds4[4 * p8 + 1];
    float4 d2 = ds4[4 * p8 + 2];
    float4 d3 = ds4[4 * p8 + 3];
    float4 u0 = u4[4 * p8 + 0];
    float4 u1 = u4[4 * p8 + 1];
    float4 u2 = u4[4 * p8 + 2];
    float4 u3 = u4[4 * p8 + 3];
    float4 sa = s4[2 * p8 + 0];
    float4 sb = s4[2 * p8 + 1];

    float Tb = T[b];
    int   nc = ncut[b];
    int   n0 = p8 << 3;              // first token index of this thread

    bool e0 = (sa.x > Tb) || (sa.x == Tb && (n0 + 0) <= nc);
    bool e1 = (sa.y > Tb) || (sa.y == Tb && (n0 + 1) <= nc);
    bool e2 = (sa.z > Tb) || (sa.z == Tb && (n0 + 2) <= nc);
    bool e3 = (sa.w > Tb) || (sa.w == Tb && (n0 + 3) <= nc);
    bool e4 = (sb.x > Tb) || (sb.x == Tb && (n0 + 4) <= nc);
    bool e5 = (sb.y > Tb) || (sb.y == Tb && (n0 + 5) <= nc);
    bool e6 = (sb.z > Tb) || (sb.z == Tb && (n0 + 6) <= nc);
    bool e7 = (sb.w > Tb) || (sb.w == Tb && (n0 + 7) <= nc);

    float acc = token_loss(d0.x, d0.y, u0.x, u0.y, e0)
              + token_loss(d0.z, d0.w, u0.z, u0.w, e1)
              + token_loss(d1.x, d1.y, u1.x, u1.y, e2)
              + token_loss(d1.z, d1.w, u1.z, u1.w, e3)
              + token_loss(d2.x, d2.y, u2.x, u2.y, e4)
              + token_loss(d2.z, d2.w, u2.z, u2.w, e5)
              + token_loss(d3.x, d3.y, u3.x, u3.y, e6)
              + token_loss(d3.z, d3.w, u3.z, u3.w, e7);

    for (int off = 32; off > 0; off >>= 1) acc += __shfl_down(acc, off, 64);
    __shared__ float red[4];
    int lane = threadIdx.x & 63, wv = threadIdx.x >> 6;
    if (lane == 0) red[wv] = acc;
    __syncthreads();
    if (threadIdx.x == 0)
        partials[blockIdx.x] = red[0] + red[1] + red[2] + red[3];
}

// --- Pass 3: reduce LOSS_BLOCKS partials into out[0] (single block) ---
__global__ void reduce_kernel(const float* __restrict__ partials, float* __restrict__ out) {
    float acc = 0.f;
    for (int i = threadIdx.x; i < LOSS_BLOCKS; i += blockDim.x) acc += partials[i];
    for (int off = 32; off > 0; off >>= 1) acc += __shfl_down(acc, off, 64);
    __shared__ float red[16];
    int lane = threadIdx.x & 63, wv = threadIdx.x >> 6;
    if (lane == 0) red[wv] = acc;
    __syncthreads();
    if (threadIdx.x == 0) {
        float s = 0.f;
        for (int w = 0; w < (int)(blockDim.x >> 6); w++) s += red[w];
        out[0] = s;
    }
}

extern "C" void kernel_launch(void* const* d_in, const int* in_sizes, int n_in,
                              void* d_out, int out_size, void* d_ws, size_t ws_size,
                              hipStream_t stream) {
    const float* ds   = (const float*)d_in[0];   // [B, N, 2]
    const float* smap = (const float*)d_in[1];   // [B, 1, H, W] == [B, N]
    const float* u    = (const float*)d_in[2];   // [B, N, 2]
    const int*   kptr = (const int*)d_in[3];     // scalar K

    // workspace layout
    float* T    = (float*)d_ws;                  // BATCH
    int*   ncut = (int*)(T + BATCH);             // BATCH
    float* partials = (float*)(ncut + BATCH);    // LOSS_BLOCKS

    prep_kernel<<<BATCH, PT, 0, stream>>>(smap, kptr, T, ncut);
    loss_kernel<<<LOSS_BLOCKS, 256, 0, stream>>>(ds, u, smap, T, ncut, partials);
    reduce_kernel<<<1, 1024, 0, stream>>>(partials, (float*)d_out);
}

// Round 6
// 213.051 us; speedup vs baseline: 3.7984x; 1.0978x over previous
//
#include <hip/hip_runtime.h>

#define NB    4096      // histogram buckets over [0,1)
#define CAP   1024      // per-batch collect capacity (expected ~64 in threshold bucket)
#define BATCH 32
#define NTOK  262144    // 512*512
#define HB    512       // hist blocks (16 per batch)
#define HPB   16        // hist blocks per batch
#define LOSS_BLOCKS 4096   // B*NTOK / 8 tokens-per-thread / 256 threads

typedef float floatx4 __attribute__((ext_vector_type(4)));  // nt-load-compatible

__device__ __forceinline__ int bucket_of(float v) {
    int b = (int)(v * (float)NB);
    return b > NB - 1 ? NB - 1 : b;
}

// --- Pass 1: per-block PRIVATE histograms (no global atomics, no memset) ---
// 512 blocks x 256 thr; block owns a 16384-float slice; writes its own 4096-int copy.
__global__ void hist_kernel(const float* __restrict__ smap, int* __restrict__ ghist) {
    __shared__ int lh[NB];
    for (int i = threadIdx.x; i < NB; i += 256) lh[i] = 0;
    __syncthreads();
    const int b  = blockIdx.x / HPB;
    const int cb = blockIdx.x % HPB;
    const int chunk = NTOK / HPB;                 // 16384 floats
    const float4* src = (const float4*)(smap + (size_t)b * NTOK + (size_t)cb * chunk);
    for (int i = threadIdx.x; i < chunk / 4; i += 256) {
        float4 v = src[i];
        atomicAdd(&lh[bucket_of(v.x)], 1);
        atomicAdd(&lh[bucket_of(v.y)], 1);
        atomicAdd(&lh[bucket_of(v.z)], 1);
        atomicAdd(&lh[bucket_of(v.w)], 1);
    }
    __syncthreads();
    int* out = ghist + (size_t)blockIdx.x * NB;
    for (int i = threadIdx.x; i < NB; i += 256) out[i] = lh[i];  // coalesced store
}

// --- Pass 2: sum 16 private copies, suffix-scan, emit (tb, R); zero cnt[b] ---
// 32 blocks x 1024 thr (one block per batch).
__global__ __launch_bounds__(1024) void select_kernel(const int* __restrict__ ghist,
                                                      const int* __restrict__ kptr,
                                                      int* __restrict__ tbR,
                                                      int* __restrict__ cnt) {
    __shared__ int hist[NB];
    __shared__ int sA[1024];
    __shared__ int sB[1024];
    const int tid = threadIdx.x;
    const int b   = blockIdx.x;
    if (tid == 0) cnt[b] = 0;

    const int C = NB / 1024;  // 4 buckets per thread
    int base = tid * C;
    const int* gh0 = ghist + (size_t)b * HPB * NB;
#pragma unroll
    for (int i = 0; i < C; i++) {
        int s = 0;
        for (int c = 0; c < HPB; c++) s += gh0[c * NB + base + i];
        hist[base + i] = s;
    }
    int csum = hist[base] + hist[base + 1] + hist[base + 2] + hist[base + 3];
    sA[tid] = csum;
    __syncthreads();

    // Hillis-Steele inclusive SUFFIX scan over 1024 chunk sums
    int* pin = sA; int* pout = sB;
    for (int st = 1; st < 1024; st <<= 1) {
        int v = pin[tid] + ((tid + st < 1024) ? pin[tid + st] : 0);
        pout[tid] = v;
        __syncthreads();
        int* t_ = pin; pin = pout; pout = t_;
    }
    int above = (tid < 1023) ? pin[tid + 1] : 0;  // strictly above this chunk

    const int K = *kptr;
    int cum = above;
    for (int i = C - 1; i >= 0; i--) {
        int hb = hist[base + i];
        if (cum < K && cum + hb >= K) {
            tbR[2 * b]     = base + i;   // threshold bucket
            tbR[2 * b + 1] = K - cum;    // residual rank R (1..hist[tb])
        }
        cum += hb;
    }
}

// --- Pass 3: collect (value, index) of elements in the threshold bucket ---
// 256 blocks x 256 thr (8 per batch); smap is L3-hot from pass 1.
__global__ void collect_kernel(const float* __restrict__ smap, const int* __restrict__ tbR,
                               int* __restrict__ cnt, float* __restrict__ cval,
                               int* __restrict__ cidx) {
    const int cbpb = 8;
    const int b  = blockIdx.x / cbpb;
    const int cb = blockIdx.x % cbpb;
    const int chunk = NTOK / cbpb;                 // 32768 floats
    const int tb = tbR[2 * b];
    const float4* src = (const float4*)(smap + (size_t)b * NTOK + (size_t)cb * chunk);
    const int base_n = cb * chunk;
    for (int i = threadIdx.x; i < chunk / 4; i += 256) {
        float4 v = src[i];
        float vals[4] = {v.x, v.y, v.z, v.w};
#pragma unroll
        for (int s = 0; s < 4; s++) {
            if (bucket_of(vals[s]) == tb) {
                int p = atomicAdd(&cnt[b], 1);
                if (p < CAP) {
                    cval[b * CAP + p] = vals[s];
                    cidx[b * CAP + p] = base_n + 4 * i + s;
                }
            }
        }
    }
}

// --- Pass 4: exact rank-(R-1) element under (value desc, index asc) ---
__global__ void refine_kernel(const int* __restrict__ tbR, const int* __restrict__ cnt,
                              const float* __restrict__ cval, const int* __restrict__ cidx,
                              float* __restrict__ T, int* __restrict__ ncut) {
    const int b = blockIdx.x;
    const int R = tbR[2 * b + 1];
    int M = cnt[b];
    bool ovf = (M > CAP);
    if (M > CAP) M = CAP;
    __shared__ float sv[CAP];
    __shared__ int   si[CAP];
    for (int i = threadIdx.x; i < M; i += 256) {
        sv[i] = cval[b * CAP + i];
        si[i] = cidx[b * CAP + i];
    }
    __syncthreads();
    if (ovf || R > M || R < 1) {   // statistically unreachable fallback
        if (threadIdx.x == 0) { T[b] = (float)tbR[2 * b] / (float)NB; ncut[b] = 0x7fffffff; }
        return;
    }
    for (int i = threadIdx.x; i < M; i += 256) {
        float vi = sv[i]; int ii = si[i];
        int r = 0;
        for (int j = 0; j < M; j++) {
            float vj = sv[j];
            r += (vj > vi) || (vj == vi && si[j] < ii);
        }
        if (r == R - 1) { T[b] = vi; ncut[b] = ii; }  // unique rank -> one writer
    }
}

__device__ __forceinline__ float token_loss(float d0, float d1, float u0, float u1,
                                            bool sel) {
    float g0 = -__logf(-__logf(u0));
    float g1 = -__logf(-__logf(u1));
    float dd = (d0 + g0) - (d1 + g1);
    float l  = __logf(1.f + __expf(-fabsf(dd)));
    float lp0 = (dd >= 0.f) ? -l      : dd - l;
    float lp1 = (dd >= 0.f) ? -l - dd : -l;
    lp0 = fmaxf(lp0, -100.f); lp1 = fmaxf(lp1, -100.f);
    return sel ? -lp0 : -lp1;
}

// --- Pass 5: fused loss, 8 tokens/thread, nontemporal streaming of ds/u ---
__global__ void loss_kernel(const float* __restrict__ ds, const float* __restrict__ u,
                            const float* __restrict__ smap, const float* __restrict__ T,
                            const int* __restrict__ ncut, float* __restrict__ partials) {
    int tid = blockIdx.x * blockDim.x + threadIdx.x;  // one thread = 8 tokens
    int b  = tid >> 15;              // 32768 threads per batch
    int p8 = tid & 32767;
    const floatx4* ds4 = (const floatx4*)(ds + (size_t)b * NTOK * 2);
    const floatx4* u4  = (const floatx4*)(u  + (size_t)b * NTOK * 2);
    const float4*  s4  = (const float4*)(smap + (size_t)b * NTOK);

    floatx4 d0 = __builtin_nontemporal_load(&ds4[4 * p8 + 0]);
    floatx4 d1 = __builtin_nontemporal_load(&ds4[4 * p8 + 1]);
    floatx4 d2 = __builtin_nontemporal_load(&ds4[4 * p8 + 2]);
    floatx4 d3 = __builtin_nontemporal_load(&ds4[4 * p8 + 3]);
    floatx4 u0 = __builtin_nontemporal_load(&u4[4 * p8 + 0]);
    floatx4 u1 = __builtin_nontemporal_load(&u4[4 * p8 + 1]);
    floatx4 u2 = __builtin_nontemporal_load(&u4[4 * p8 + 2]);
    floatx4 u3 = __builtin_nontemporal_load(&u4[4 * p8 + 3]);
    float4 sa = s4[2 * p8 + 0];
    float4 sb = s4[2 * p8 + 1];

    float Tb = T[b];
    int   nc = ncut[b];
    int   n0 = p8 << 3;

    bool e0 = (sa.x > Tb) || (sa.x == Tb && (n0 + 0) <= nc);
    bool e1 = (sa.y > Tb) || (sa.y == Tb && (n0 + 1) <= nc);
    bool e2 = (sa.z > Tb) || (sa.z == Tb && (n0 + 2) <= nc);
    bool e3 = (sa.w > Tb) || (sa.w == Tb && (n0 + 3) <= nc);
    bool e4 = (sb.x > Tb) || (sb.x == Tb && (n0 + 4) <= nc);
    bool e5 = (sb.y > Tb) || (sb.y == Tb && (n0 + 5) <= nc);
    bool e6 = (sb.z > Tb) || (sb.z == Tb && (n0 + 6) <= nc);
    bool e7 = (sb.w > Tb) || (sb.w == Tb && (n0 + 7) <= nc);

    float acc = token_loss(d0.x, d0.y, u0.x, u0.y, e0)
              + token_loss(d0.z, d0.w, u0.z, u0.w, e1)
              + token_loss(d1.x, d1.y, u1.x, u1.y, e2)
              + token_loss(d1.z, d1.w, u1.z, u1.w, e3)
              + token_loss(d2.x, d2.y, u2.x, u2.y, e4)
              + token_loss(d2.z, d2.w, u2.z, u2.w, e5)
              + token_loss(d3.x, d3.y, u3.x, u3.y, e6)
              + token_loss(d3.z, d3.w, u3.z, u3.w, e7);

    for (int off = 32; off > 0; off >>= 1) acc += __shfl_down(acc, off, 64);
    __shared__ float red[4];
    int lane = threadIdx.x & 63, wv = threadIdx.x >> 6;
    if (lane == 0) red[wv] = acc;
    __syncthreads();
    if (threadIdx.x == 0)
        partials[blockIdx.x] = red[0] + red[1] + red[2] + red[3];
}

// --- Pass 6: reduce partials into out[0] ---
__global__ void reduce_kernel(const float* __restrict__ partials, float* __restrict__ out) {
    float acc = 0.f;
    for (int i = threadIdx.x; i < LOSS_BLOCKS; i += blockDim.x) acc += partials[i];
    for (int off = 32; off > 0; off >>= 1) acc += __shfl_down(acc, off, 64);
    __shared__ float red[16];
    int lane = threadIdx.x & 63, wv = threadIdx.x >> 6;
    if (lane == 0) red[wv] = acc;
    __syncthreads();
    if (threadIdx.x == 0) {
        float s = 0.f;
        for (int w = 0; w < (int)(blockDim.x >> 6); w++) s += red[w];
        out[0] = s;
    }
}

extern "C" void kernel_launch(void* const* d_in, const int* in_sizes, int n_in,
                              void* d_out, int out_size, void* d_ws, size_t ws_size,
                              hipStream_t stream) {
    const float* ds   = (const float*)d_in[0];   // [B, N, 2]
    const float* smap = (const float*)d_in[1];   // [B, 1, H, W] == [B, N]
    const float* u    = (const float*)d_in[2];   // [B, N, 2]
    const int*   kptr = (const int*)d_in[3];     // scalar K

    // workspace layout
    int*   ghist = (int*)d_ws;                   // HB * NB private histograms
    int*   cnt   = ghist + HB * NB;              // BATCH
    int*   tbR   = cnt + BATCH;                  // 2*BATCH
    float* T     = (float*)(tbR + 2 * BATCH);    // BATCH
    int*   ncut  = (int*)(T + BATCH);            // BATCH
    float* cval  = (float*)(ncut + BATCH);       // BATCH*CAP
    int*   cidx  = (int*)(cval + BATCH * CAP);   // BATCH*CAP
    float* partials = (float*)(cidx + BATCH * CAP);  // LOSS_BLOCKS

    hist_kernel<<<HB, 256, 0, stream>>>(smap, ghist);
    select_kernel<<<BATCH, 1024, 0, stream>>>(ghist, kptr, tbR, cnt);
    collect_kernel<<<256, 256, 0, stream>>>(smap, tbR, cnt, cval, cidx);
    refine_kernel<<<BATCH, 256, 0, stream>>>(tbR, cnt, cval, cidx, T, ncut);
    loss_kernel<<<LOSS_BLOCKS, 256, 0, stream>>>(ds, u, smap, T, ncut, partials);
    reduce_kernel<<<1, 1024, 0, stream>>>(partials, (float*)d_out);
}